// Round 1
// baseline (2348.477 us; speedup 1.0000x reference)
//
#include <hip/hip_runtime.h>
#include <math.h>

#define HIDDEN 64

// ---------------- CSR build ----------------

__global__ __launch_bounds__(256) void k_deg_init(int* deg, int n) {
    int i = blockIdx.x * 256 + threadIdx.x;
    if (i < n) deg[i] = 1;  // self-loop
}

__global__ __launch_bounds__(256) void k_hist(const int* __restrict__ dst, int* deg, int E) {
    int i = blockIdx.x * 256 + threadIdx.x;
    if (i < E) atomicAdd(&deg[dst[i]], 1);
}

__global__ __launch_bounds__(256) void k_dinv(const int* __restrict__ deg, float* dinv, int n) {
    int i = blockIdx.x * 256 + threadIdx.x;
    if (i < n) {
        int d = deg[i];
        dinv[i] = d > 0 ? 1.0f / sqrtf((float)d) : 0.0f;
    }
}

#define SCAN_BS 256
__global__ __launch_bounds__(SCAN_BS) void k_scan1(const int* __restrict__ deg, int* partial,
                                                   int* blocksums, int n) {
    __shared__ int sm[SCAN_BS];
    int i = blockIdx.x * SCAN_BS + threadIdx.x;
    int v = (i < n) ? deg[i] : 0;
    sm[threadIdx.x] = v;
    __syncthreads();
    for (int off = 1; off < SCAN_BS; off <<= 1) {
        int t = 0;
        if ((int)threadIdx.x >= off) t = sm[threadIdx.x - off];
        __syncthreads();
        sm[threadIdx.x] += t;
        __syncthreads();
    }
    if (i < n) partial[i] = sm[threadIdx.x];
    if (threadIdx.x == SCAN_BS - 1) blocksums[blockIdx.x] = sm[SCAN_BS - 1];
}

__global__ __launch_bounds__(512) void k_scan2(int* blocksums, int nb) {
    __shared__ int sm[512];
    int v = ((int)threadIdx.x < nb) ? blocksums[threadIdx.x] : 0;
    sm[threadIdx.x] = v;
    __syncthreads();
    for (int off = 1; off < 512; off <<= 1) {
        int t = 0;
        if ((int)threadIdx.x >= off) t = sm[threadIdx.x - off];
        __syncthreads();
        sm[threadIdx.x] += t;
        __syncthreads();
    }
    if ((int)threadIdx.x < nb) blocksums[threadIdx.x] = threadIdx.x ? sm[threadIdx.x - 1] : 0;
}

__global__ __launch_bounds__(256) void k_scan3(const int* __restrict__ partial,
                                               const int* __restrict__ blocksums,
                                               const int* __restrict__ deg,
                                               int* rowptr, int* cursor, int n) {
    int i = blockIdx.x * 256 + threadIdx.x;
    if (i < n) {
        int incl = partial[i] + blocksums[i / SCAN_BS];
        rowptr[i + 1] = incl;
        cursor[i] = incl - deg[i];
        if (i == 0) rowptr[0] = 0;
    }
}

__global__ __launch_bounds__(256) void k_fill(const int* __restrict__ srcA,
                                              const int* __restrict__ dstA,
                                              const float* __restrict__ dinv,
                                              int* cursor, int* col, float* w,
                                              int E, int n) {
    int i = blockIdx.x * 256 + threadIdx.x;
    int total = E + n;
    if (i >= total) return;
    int s, d;
    if (i < E) { s = srcA[i]; d = dstA[i]; }
    else       { s = d = i - E; }
    int pos = atomicAdd(&cursor[d], 1);
    col[pos] = s;
    w[pos] = dinv[s] * dinv[d];
}

// ---------------- layer kernels ----------------

// aggregate raw x (3-wide): out3[n] = sum_j w * x[col[j]]
__global__ __launch_bounds__(256) void k_agg3(const float* __restrict__ x,
                                              const int* __restrict__ rowptr,
                                              const int* __restrict__ col,
                                              const float* __restrict__ w,
                                              float* __restrict__ out3, int n) {
    int i = blockIdx.x * 256 + threadIdx.x;
    if (i >= n) return;
    float a0 = 0.f, a1 = 0.f, a2 = 0.f;
    int beg = rowptr[i], end = rowptr[i + 1];
    for (int j = beg; j < end; ++j) {
        int s = col[j];
        float ww = w[j];
        a0 += ww * x[s * 3 + 0];
        a1 += ww * x[s * 3 + 1];
        a2 += ww * x[s * 3 + 2];
    }
    out3[i * 3 + 0] = a0;
    out3[i * 3 + 1] = a1;
    out3[i * 3 + 2] = a2;
}

// input transform: h[n][f] = relu( sum_k agg3[n][k]*Win[k][f] + bin[f] )
__global__ __launch_bounds__(256) void k_tin(const float* __restrict__ agg3v,
                                             const float* __restrict__ Win,
                                             const float* __restrict__ bin,
                                             float* __restrict__ h, int n) {
    int idx = blockIdx.x * 256 + threadIdx.x;
    int node = idx >> 6, f = idx & 63;
    if (node >= n) return;
    float v = bin[f];
    v += agg3v[node * 3 + 0] * Win[0 * 64 + f];
    v += agg3v[node * 3 + 1] * Win[1 * 64 + f];
    v += agg3v[node * 3 + 2] * Win[2 * 64 + f];
    h[(size_t)node * 64 + f] = fmaxf(v, 0.f);
}

// dense 64x64 matmul: t = h @ W  (16 nodes per block, thread = (node, feat-quad))
__global__ __launch_bounds__(256) void k_matmul64(const float* __restrict__ h,
                                                  const float* __restrict__ W,
                                                  float* __restrict__ t, int n) {
    __shared__ float Wl[64 * 64];     // [k][f]
    __shared__ float Hl[16][68];      // padded to kill bank conflicts
    int tid = threadIdx.x;
    for (int i = tid * 4; i < 4096; i += 1024)
        *(float4*)&Wl[i] = *(const float4*)&W[i];
    int nodeBase = blockIdx.x * 16;
    {
        int idx = tid * 4;            // 1024 floats = 16 nodes x 64
        int nl = idx >> 6, k = idx & 63;
        int node = nodeBase + nl;
        float4 v = make_float4(0.f, 0.f, 0.f, 0.f);
        if (node < n) v = *(const float4*)&h[(size_t)node * 64 + k];
        *(float4*)&Hl[nl][k] = v;
    }
    __syncthreads();
    int nl = tid >> 4;
    int fq = (tid & 15) * 4;
    float4 acc = make_float4(0.f, 0.f, 0.f, 0.f);
#pragma unroll
    for (int k = 0; k < 64; ++k) {
        float hv = Hl[nl][k];
        float4 wv = *(const float4*)&Wl[k * 64 + fq];
        acc.x += hv * wv.x;
        acc.y += hv * wv.y;
        acc.z += hv * wv.z;
        acc.w += hv * wv.w;
    }
    int node = nodeBase + nl;
    if (node < n) *(float4*)&t[(size_t)node * 64 + fq] = acc;
}

// 64-wide pull aggregation + bias + relu: one wave per node, lane = feature
__global__ __launch_bounds__(256) void k_agg64(const float* __restrict__ t,
                                               const int* __restrict__ rowptr,
                                               const int* __restrict__ col,
                                               const float* __restrict__ w,
                                               const float* __restrict__ bias,
                                               float* __restrict__ hout, int n) {
    int node = blockIdx.x * 4 + (threadIdx.x >> 6);
    int lane = threadIdx.x & 63;
    if (node >= n) return;
    int beg = rowptr[node], end = rowptr[node + 1];
    float acc = 0.f;
    int j = beg;
    if (j < end) {
        int s = col[j];
        float ww = w[j];
        for (++j; j < end; ++j) {
            int s2 = col[j];          // prefetch next edge
            float w2 = w[j];
            acc += ww * t[(size_t)s * 64 + lane];
            s = s2; ww = w2;
        }
        acc += ww * t[(size_t)s * 64 + lane];
    }
    float v = acc + bias[lane];
    hout[(size_t)node * 64 + lane] = fmaxf(v, 0.f);
}

// output transform: t6 = h @ Wout  (64 -> 6), thread per node
__global__ __launch_bounds__(256) void k_tout(const float* __restrict__ h,
                                              const float* __restrict__ Wout,
                                              float* __restrict__ t6, int n) {
    int node = blockIdx.x * 256 + threadIdx.x;
    if (node >= n) return;
    float acc[6] = {0.f, 0.f, 0.f, 0.f, 0.f, 0.f};
#pragma unroll
    for (int k4 = 0; k4 < 16; ++k4) {
        float4 hv = *(const float4*)&h[(size_t)node * 64 + k4 * 4];
        float hq[4] = {hv.x, hv.y, hv.z, hv.w};
#pragma unroll
        for (int q = 0; q < 4; ++q) {
            int k = k4 * 4 + q;
#pragma unroll
            for (int f = 0; f < 6; ++f) acc[f] += hq[q] * Wout[k * 6 + f];
        }
    }
#pragma unroll
    for (int f = 0; f < 6; ++f) t6[node * 6 + f] = acc[f];
}

// 6-wide aggregation + bias + sigmoid, thread per node
__global__ __launch_bounds__(256) void k_agg6(const float* __restrict__ t6,
                                              const int* __restrict__ rowptr,
                                              const int* __restrict__ col,
                                              const float* __restrict__ w,
                                              const float* __restrict__ bout,
                                              float* __restrict__ out, int n) {
    int i = blockIdx.x * 256 + threadIdx.x;
    if (i >= n) return;
    float a[6] = {0.f, 0.f, 0.f, 0.f, 0.f, 0.f};
    int beg = rowptr[i], end = rowptr[i + 1];
    for (int j = beg; j < end; ++j) {
        int s = col[j];
        float ww = w[j];
#pragma unroll
        for (int f = 0; f < 6; ++f) a[f] += ww * t6[s * 6 + f];
    }
#pragma unroll
    for (int f = 0; f < 6; ++f) {
        float v = a[f] + bout[f];
        out[i * 6 + f] = 1.0f / (1.0f + expf(-v));
    }
}

// ---------------- host launcher ----------------

extern "C" void kernel_launch(void* const* d_in, const int* in_sizes, int n_in,
                              void* d_out, int out_size, void* d_ws, size_t ws_size,
                              hipStream_t stream) {
    const float* x    = (const float*)d_in[0];
    const int*   eidx = (const int*)d_in[1];
    const float* Win  = (const float*)d_in[2];
    const float* bin  = (const float*)d_in[3];
    const float* Whid = (const float*)d_in[4];
    const float* bhid = (const float*)d_in[5];
    const float* Wout = (const float*)d_in[6];
    const float* bout = (const float*)d_in[7];
    float* out = (float*)d_out;

    const int N = in_sizes[0] / 3;
    const int E = in_sizes[1] / 2;
    const int* srcA = eidx;
    const int* dstA = eidx + E;
    const int TOT = E + N;

    // workspace carve-up (256B aligned)
    char* p = (char*)d_ws;
    auto alloc = [&](size_t bytes) -> void* {
        void* r = (void*)p;
        p += (bytes + 255) & ~(size_t)255;
        return r;
    };
    int*   deg      = (int*)alloc((size_t)N * 4);
    float* dinv     = (float*)alloc((size_t)N * 4);
    int*   rowptr   = (int*)alloc((size_t)(N + 1) * 4);
    int*   cursor   = (int*)alloc((size_t)N * 4);
    int*   partial  = (int*)alloc((size_t)N * 4);
    int*   bsums    = (int*)alloc((size_t)512 * 4);
    int*   col      = (int*)alloc((size_t)TOT * 4);
    float* w        = (float*)alloc((size_t)TOT * 4);
    float* agg3buf  = (float*)alloc((size_t)N * 3 * 4);
    float* bufA     = (float*)alloc((size_t)N * 64 * 4);
    float* bufB     = (float*)alloc((size_t)N * 64 * 4);
    float* t6       = (float*)alloc((size_t)N * 6 * 4);

    const int NB_N = (N + 255) / 256;
    const int NB_E = (E + 255) / 256;
    const int NB_T = (TOT + 255) / 256;

    // CSR build
    k_deg_init<<<NB_N, 256, 0, stream>>>(deg, N);
    k_hist<<<NB_E, 256, 0, stream>>>(dstA, deg, E);
    k_dinv<<<NB_N, 256, 0, stream>>>(deg, dinv, N);
    k_scan1<<<NB_N, SCAN_BS, 0, stream>>>(deg, partial, bsums, N);
    k_scan2<<<1, 512, 0, stream>>>(bsums, NB_N);
    k_scan3<<<NB_N, 256, 0, stream>>>(partial, bsums, deg, rowptr, cursor, N);
    k_fill<<<NB_T, 256, 0, stream>>>(srcA, dstA, dinv, cursor, col, w, E, N);

    // input layer: aggregate raw x (3-wide), then 3->64 transform + bias + relu
    k_agg3<<<NB_N, 256, 0, stream>>>(x, rowptr, col, w, agg3buf, N);
    k_tin<<<(N * 64 + 255) / 256, 256, 0, stream>>>(agg3buf, Win, bin, bufA, N);

    // hidden layers: t = h @ W; h = relu(agg(t) + b)
    float* h = bufA;
    float* t = bufB;
    for (int i = 0; i < 6; ++i) {
        k_matmul64<<<(N + 15) / 16, 256, 0, stream>>>(h, Whid + (size_t)i * 4096, t, N);
        k_agg64<<<(N + 3) / 4, 256, 0, stream>>>(t, rowptr, col, w, bhid + (size_t)i * 64, h, N);
    }

    // output layer: t6 = h @ Wout; out = sigmoid(agg(t6) + bout)
    k_tout<<<NB_N, 256, 0, stream>>>(h, Wout, t6, N);
    k_agg6<<<NB_N, 256, 0, stream>>>(t6, rowptr, col, w, bout, out, N);
}

// Round 2
// 1702.143 us; speedup vs baseline: 1.3797x; 1.3797x over previous
//
#include <hip/hip_runtime.h>
#include <hip/hip_fp16.h>
#include <math.h>

// ---------------- CSR build ----------------

__global__ __launch_bounds__(256) void k_deg_init(int* deg, int n) {
    int i = blockIdx.x * 256 + threadIdx.x;
    if (i < n) deg[i] = 1;  // self-loop
}

__global__ __launch_bounds__(256) void k_hist(const int* __restrict__ dst, int* deg, int E) {
    int i = blockIdx.x * 256 + threadIdx.x;
    if (i < E) atomicAdd(&deg[dst[i]], 1);
}

__global__ __launch_bounds__(256) void k_dinv(const int* __restrict__ deg, float* dinv, int n) {
    int i = blockIdx.x * 256 + threadIdx.x;
    if (i < n) {
        int d = deg[i];
        dinv[i] = d > 0 ? 1.0f / sqrtf((float)d) : 0.0f;
    }
}

#define SCAN_BS 256
__global__ __launch_bounds__(SCAN_BS) void k_scan1(const int* __restrict__ deg, int* partial,
                                                   int* blocksums, int n) {
    __shared__ int sm[SCAN_BS];
    int i = blockIdx.x * SCAN_BS + threadIdx.x;
    int v = (i < n) ? deg[i] : 0;
    sm[threadIdx.x] = v;
    __syncthreads();
    for (int off = 1; off < SCAN_BS; off <<= 1) {
        int t = 0;
        if ((int)threadIdx.x >= off) t = sm[threadIdx.x - off];
        __syncthreads();
        sm[threadIdx.x] += t;
        __syncthreads();
    }
    if (i < n) partial[i] = sm[threadIdx.x];
    if (threadIdx.x == SCAN_BS - 1) blocksums[blockIdx.x] = sm[SCAN_BS - 1];
}

__global__ __launch_bounds__(512) void k_scan2(int* blocksums, int nb) {
    __shared__ int sm[512];
    int v = ((int)threadIdx.x < nb) ? blocksums[threadIdx.x] : 0;
    sm[threadIdx.x] = v;
    __syncthreads();
    for (int off = 1; off < 512; off <<= 1) {
        int t = 0;
        if ((int)threadIdx.x >= off) t = sm[threadIdx.x - off];
        __syncthreads();
        sm[threadIdx.x] += t;
        __syncthreads();
    }
    if ((int)threadIdx.x < nb) blocksums[threadIdx.x] = threadIdx.x ? sm[threadIdx.x - 1] : 0;
}

__global__ __launch_bounds__(256) void k_scan3(const int* __restrict__ partial,
                                               const int* __restrict__ blocksums,
                                               const int* __restrict__ deg,
                                               int* rowptr, int* cursor, int n) {
    int i = blockIdx.x * 256 + threadIdx.x;
    if (i < n) {
        int incl = partial[i] + blocksums[i / SCAN_BS];
        rowptr[i + 1] = incl;
        cursor[i] = incl - deg[i];
        if (i == 0) rowptr[0] = 0;
    }
}

// fill CSR col only (norm weights are factored into dinv scaling at both ends)
__global__ __launch_bounds__(256) void k_fill(const int* __restrict__ srcA,
                                              const int* __restrict__ dstA,
                                              int* cursor, int* col,
                                              int E, int n) {
    int i = blockIdx.x * 256 + threadIdx.x;
    int total = E + n;
    if (i >= total) return;
    int s, d;
    if (i < E) { s = srcA[i]; d = dstA[i]; }
    else       { s = d = i - E; }
    int pos = atomicAdd(&cursor[d], 1);
    col[pos] = s;
}

// ---------------- layer kernels ----------------

// prescale x by dinv (source-side factor): xs[i] = dinv[i]*x[i]
__global__ __launch_bounds__(256) void k_xscale(const float* __restrict__ x,
                                                const float* __restrict__ dinv,
                                                float* __restrict__ xs, int n) {
    int i = blockIdx.x * 256 + threadIdx.x;
    if (i >= n) return;
    float dv = dinv[i];
    xs[i * 3 + 0] = dv * x[i * 3 + 0];
    xs[i * 3 + 1] = dv * x[i * 3 + 1];
    xs[i * 3 + 2] = dv * x[i * 3 + 2];
}

// aggregate prescaled x (3-wide), apply dst-side dinv
__global__ __launch_bounds__(256) void k_agg3(const float* __restrict__ xs,
                                              const int* __restrict__ rowptr,
                                              const int* __restrict__ col,
                                              const float* __restrict__ dinv,
                                              float* __restrict__ out3, int n) {
    int i = blockIdx.x * 256 + threadIdx.x;
    if (i >= n) return;
    float a0 = 0.f, a1 = 0.f, a2 = 0.f;
    int beg = rowptr[i], end = rowptr[i + 1];
    for (int j = beg; j < end; ++j) {
        int s = col[j];
        a0 += xs[s * 3 + 0];
        a1 += xs[s * 3 + 1];
        a2 += xs[s * 3 + 2];
    }
    float dv = dinv[i];
    out3[i * 3 + 0] = dv * a0;
    out3[i * 3 + 1] = dv * a1;
    out3[i * 3 + 2] = dv * a2;
}

// input transform: h[n][f] = relu( agg3[n] @ Win + bin )
__global__ __launch_bounds__(256) void k_tin(const float* __restrict__ agg3v,
                                             const float* __restrict__ Win,
                                             const float* __restrict__ bin,
                                             float* __restrict__ h, int n) {
    int idx = blockIdx.x * 256 + threadIdx.x;
    int node = idx >> 6, f = idx & 63;
    if (node >= n) return;
    float v = bin[f];
    v += agg3v[node * 3 + 0] * Win[0 * 64 + f];
    v += agg3v[node * 3 + 1] * Win[1 * 64 + f];
    v += agg3v[node * 3 + 2] * Win[2 * 64 + f];
    h[(size_t)node * 64 + f] = fmaxf(v, 0.f);
}

// dense 64x64 matmul + src-side dinv scale, fp16 output:
// t16[node] = (half) ( dinv[node] * (h[node] @ W) )
__global__ __launch_bounds__(256) void k_matmul64(const float* __restrict__ h,
                                                  const float* __restrict__ W,
                                                  const float* __restrict__ dinv,
                                                  __half* __restrict__ t16, int n) {
    __shared__ float Wl[64 * 64];     // [k][f]
    __shared__ float Hl[16][68];      // padded
    int tid = threadIdx.x;
    for (int i = tid * 4; i < 4096; i += 1024)
        *(float4*)&Wl[i] = *(const float4*)&W[i];
    int nodeBase = blockIdx.x * 16;
    {
        int idx = tid * 4;            // 1024 floats = 16 nodes x 64
        int nl = idx >> 6, k = idx & 63;
        int node = nodeBase + nl;
        float4 v = make_float4(0.f, 0.f, 0.f, 0.f);
        if (node < n) v = *(const float4*)&h[(size_t)node * 64 + k];
        *(float4*)&Hl[nl][k] = v;
    }
    __syncthreads();
    int nl = tid >> 4;
    int fq = (tid & 15) * 4;
    float4 acc = make_float4(0.f, 0.f, 0.f, 0.f);
#pragma unroll
    for (int k = 0; k < 64; ++k) {
        float hv = Hl[nl][k];
        float4 wv = *(const float4*)&Wl[k * 64 + fq];
        acc.x += hv * wv.x;
        acc.y += hv * wv.y;
        acc.z += hv * wv.z;
        acc.w += hv * wv.w;
    }
    int node = nodeBase + nl;
    if (node < n) {
        float dv = dinv[node];
        __half2 h01 = __floats2half2_rn(acc.x * dv, acc.y * dv);
        __half2 h23 = __floats2half2_rn(acc.z * dv, acc.w * dv);
        __half2* dst = (__half2*)&t16[(size_t)node * 64 + fq];
        dst[0] = h01;
        dst[1] = h23;
    }
}

// 64-wide pull aggregation over fp16 rows + dst dinv + bias + relu
__global__ __launch_bounds__(256) void k_agg64(const __half* __restrict__ t16,
                                               const int* __restrict__ rowptr,
                                               const int* __restrict__ col,
                                               const float* __restrict__ dinv,
                                               const float* __restrict__ bias,
                                               float* __restrict__ hout, int n) {
    int node = blockIdx.x * 4 + (threadIdx.x >> 6);
    int lane = threadIdx.x & 63;
    if (node >= n) return;
    int beg = rowptr[node], end = rowptr[node + 1];
    float acc = 0.f;
    int j = beg;
    if (j < end) {
        int s = col[j];
        for (++j; j < end; ++j) {
            int s2 = col[j];          // prefetch next edge index
            acc += __half2float(t16[(size_t)s * 64 + lane]);
            s = s2;
        }
        acc += __half2float(t16[(size_t)s * 64 + lane]);
    }
    float v = dinv[node] * acc + bias[lane];
    hout[(size_t)node * 64 + lane] = fmaxf(v, 0.f);
}

// output transform: t6 = dinv[node] * (h @ Wout)   (64 -> 6), fp32
__global__ __launch_bounds__(256) void k_tout(const float* __restrict__ h,
                                              const float* __restrict__ Wout,
                                              const float* __restrict__ dinv,
                                              float* __restrict__ t6, int n) {
    int node = blockIdx.x * 256 + threadIdx.x;
    if (node >= n) return;
    float acc[6] = {0.f, 0.f, 0.f, 0.f, 0.f, 0.f};
#pragma unroll
    for (int k4 = 0; k4 < 16; ++k4) {
        float4 hv = *(const float4*)&h[(size_t)node * 64 + k4 * 4];
        float hq[4] = {hv.x, hv.y, hv.z, hv.w};
#pragma unroll
        for (int q = 0; q < 4; ++q) {
            int k = k4 * 4 + q;
#pragma unroll
            for (int f = 0; f < 6; ++f) acc[f] += hq[q] * Wout[k * 6 + f];
        }
    }
    float dv = dinv[node];
#pragma unroll
    for (int f = 0; f < 6; ++f) t6[node * 6 + f] = dv * acc[f];
}

// 6-wide aggregation + dst dinv + bias + sigmoid
__global__ __launch_bounds__(256) void k_agg6(const float* __restrict__ t6,
                                              const int* __restrict__ rowptr,
                                              const int* __restrict__ col,
                                              const float* __restrict__ dinv,
                                              const float* __restrict__ bout,
                                              float* __restrict__ out, int n) {
    int i = blockIdx.x * 256 + threadIdx.x;
    if (i >= n) return;
    float a[6] = {0.f, 0.f, 0.f, 0.f, 0.f, 0.f};
    int beg = rowptr[i], end = rowptr[i + 1];
    for (int j = beg; j < end; ++j) {
        int s = col[j];
#pragma unroll
        for (int f = 0; f < 6; ++f) a[f] += t6[s * 6 + f];
    }
    float dv = dinv[i];
#pragma unroll
    for (int f = 0; f < 6; ++f) {
        float v = dv * a[f] + bout[f];
        out[i * 6 + f] = 1.0f / (1.0f + expf(-v));
    }
}

// ---------------- host launcher ----------------

extern "C" void kernel_launch(void* const* d_in, const int* in_sizes, int n_in,
                              void* d_out, int out_size, void* d_ws, size_t ws_size,
                              hipStream_t stream) {
    const float* x    = (const float*)d_in[0];
    const int*   eidx = (const int*)d_in[1];
    const float* Win  = (const float*)d_in[2];
    const float* bin  = (const float*)d_in[3];
    const float* Whid = (const float*)d_in[4];
    const float* bhid = (const float*)d_in[5];
    const float* Wout = (const float*)d_in[6];
    const float* bout = (const float*)d_in[7];
    float* out = (float*)d_out;

    const int N = in_sizes[0] / 3;
    const int E = in_sizes[1] / 2;
    const int* srcA = eidx;
    const int* dstA = eidx + E;
    const int TOT = E + N;

    // workspace carve-up (256B aligned)
    char* p = (char*)d_ws;
    auto alloc = [&](size_t bytes) -> void* {
        void* r = (void*)p;
        p += (bytes + 255) & ~(size_t)255;
        return r;
    };
    int*    deg      = (int*)alloc((size_t)N * 4);
    float*  dinv     = (float*)alloc((size_t)N * 4);
    int*    rowptr   = (int*)alloc((size_t)(N + 1) * 4);
    int*    cursor   = (int*)alloc((size_t)N * 4);
    int*    partial  = (int*)alloc((size_t)N * 4);
    int*    bsums    = (int*)alloc((size_t)512 * 4);
    int*    col      = (int*)alloc((size_t)TOT * 4);
    float*  xs       = (float*)alloc((size_t)N * 3 * 4);
    float*  agg3buf  = (float*)alloc((size_t)N * 3 * 4);
    float*  bufA     = (float*)alloc((size_t)N * 64 * 4);   // h (fp32)
    __half* t16      = (__half*)alloc((size_t)N * 64 * 2);  // scaled transform (fp16)
    float*  t6       = (float*)alloc((size_t)N * 6 * 4);

    const int NB_N = (N + 255) / 256;
    const int NB_E = (E + 255) / 256;
    const int NB_T = (TOT + 255) / 256;

    // CSR build
    k_deg_init<<<NB_N, 256, 0, stream>>>(deg, N);
    k_hist<<<NB_E, 256, 0, stream>>>(dstA, deg, E);
    k_dinv<<<NB_N, 256, 0, stream>>>(deg, dinv, N);
    k_scan1<<<NB_N, SCAN_BS, 0, stream>>>(deg, partial, bsums, N);
    k_scan2<<<1, 512, 0, stream>>>(bsums, NB_N);
    k_scan3<<<NB_N, 256, 0, stream>>>(partial, bsums, deg, rowptr, cursor, N);
    k_fill<<<NB_T, 256, 0, stream>>>(srcA, dstA, cursor, col, E, N);

    // input layer: prescale x, aggregate 3-wide, transform 3->64 + bias + relu
    k_xscale<<<NB_N, 256, 0, stream>>>(x, dinv, xs, N);
    k_agg3<<<NB_N, 256, 0, stream>>>(xs, rowptr, col, dinv, agg3buf, N);
    k_tin<<<(N * 64 + 255) / 256, 256, 0, stream>>>(agg3buf, Win, bin, bufA, N);

    // hidden layers: t16 = fp16(dinv * (h @ W)); h = relu(dinv*agg(t16) + b)
    float* h = bufA;
    for (int i = 0; i < 6; ++i) {
        k_matmul64<<<(N + 15) / 16, 256, 0, stream>>>(h, Whid + (size_t)i * 4096, dinv, t16, N);
        k_agg64<<<(N + 3) / 4, 256, 0, stream>>>(t16, rowptr, col, dinv, bhid + (size_t)i * 64, h, N);
    }

    // output layer
    k_tout<<<NB_N, 256, 0, stream>>>(h, Wout, dinv, t6, N);
    k_agg6<<<NB_N, 256, 0, stream>>>(t6, rowptr, col, dinv, bout, out, N);
}